// Round 3
// baseline (498.408 us; speedup 1.0000x reference)
//
#include <hip/hip_runtime.h>

typedef int v4i __attribute__((ext_vector_type(4)));
typedef int v16i __attribute__((ext_vector_type(16)));

#define EPS_F 1e-8f

#define GLOAD_LDS16(g, l)                                              \
    __builtin_amdgcn_global_load_lds(                                  \
        (const __attribute__((address_space(1))) void*)(g),            \
        (__attribute__((address_space(3))) void*)(l), 16, 0, 0)

// ---------------- kernel 1: sum |w| in fp64 ----------------
__global__ void __launch_bounds__(256) wabs_sum_kernel(const float* __restrict__ w,
                                                       double* __restrict__ out, int n4) {
    const float4* w4 = (const float4*)w;
    double s = 0.0;
    int idx = blockIdx.x * 256 + threadIdx.x;
    int stride = gridDim.x * 256;
    for (int i = idx; i < n4; i += stride) {
        float4 v = w4[i];
        s += (double)fabsf(v.x) + (double)fabsf(v.y) +
             (double)fabsf(v.z) + (double)fabsf(v.w);
    }
    for (int off = 32; off > 0; off >>= 1)
        s += __shfl_down(s, off);
    __shared__ double sm[4];
    if ((threadIdx.x & 63) == 0) sm[threadIdx.x >> 6] = s;
    __syncthreads();
    if (threadIdx.x == 0) {
        atomicAdd(out, sm[0] + sm[1] + sm[2] + sm[3]);
    }
}

// ---------------- kernel 2: ternary quant + flatmm-shuffle pack ----------------
// Bp layout: for n-group g (32 rows), k-chunk ks (32 bytes), half (16B):
//   1KB segment holding lanes l32 = row g*32+l32, bytes k = ks*32+half*16 .. +16
// One wave-load of 64 consecutive 16B gives the exact 32x32x32 B fragment.
__global__ void __launch_bounds__(256) wpack_kernel(const float* __restrict__ w,
                                                    const double* __restrict__ wsum,
                                                    signed char* __restrict__ bp,
                                                    int N, int K) {
    const int u = blockIdx.x * 256 + threadIdx.x;     // one 16B output chunk
    const float wsf = (float)(wsum[0] / (double)((size_t)N * K)) + EPS_F;
    const float inv = 1.0f / wsf;
    const int l32 = u & 31;
    const int s = u >> 5;                 // 512B super-segment
    const int half = s & 1;
    const int ks = (s >> 1) & ((K >> 5) - 1);
    const int g = s >> 1 >> 7;            // s / (2*(K/32)), K=4096 -> >>8
    const int n = g * 32 + l32;
    const int kb = ks * 32 + half * 16;

    const float4* wv = (const float4*)(w + (size_t)n * K + kb);
    unsigned int out[4];
#pragma unroll
    for (int j = 0; j < 4; j++) {
        float4 v = wv[j];
        int q0 = min(1, max(-1, (int)rintf(v.x * inv)));
        int q1 = min(1, max(-1, (int)rintf(v.y * inv)));
        int q2 = min(1, max(-1, (int)rintf(v.z * inv)));
        int q3 = min(1, max(-1, (int)rintf(v.w * inv)));
        out[j] = (q0 & 0xff) | ((q1 & 0xff) << 8) | ((q2 & 0xff) << 16) | ((q3 & 0xff) << 24);
    }
    int4 pk = make_int4(out[0], out[1], out[2], out[3]);
    ((int4*)bp)[u] = pk;                   // fully coalesced
}

// ---------------- kernel 3: per-token int8 activation quant ----------------
__global__ void __launch_bounds__(256) xquant_kernel(const float* __restrict__ x,
                                                     signed char* __restrict__ xq,
                                                     float* __restrict__ xscale, int K) {
    int row = blockIdx.x;
    const float4* xr = (const float4*)(x + (size_t)row * K);
    unsigned int* qr = (unsigned int*)(xq + (size_t)row * K);
    int t = threadIdx.x;
    float4 v[4];
    float mx = 0.0f;
#pragma unroll
    for (int j = 0; j < 4; j++) {
        v[j] = xr[t + j * 256];
        mx = fmaxf(mx, fmaxf(fmaxf(fabsf(v[j].x), fabsf(v[j].y)),
                             fmaxf(fabsf(v[j].z), fabsf(v[j].w))));
    }
    for (int off = 32; off > 0; off >>= 1)
        mx = fmaxf(mx, __shfl_down(mx, off));
    __shared__ float sm[4];
    if ((t & 63) == 0) sm[t >> 6] = mx;
    __syncthreads();
    float scale = fmaxf(fmaxf(fmaxf(sm[0], sm[1]), fmaxf(sm[2], sm[3])), EPS_F);
    float inv = 127.0f / scale;
#pragma unroll
    for (int j = 0; j < 4; j++) {
        int q0 = min(127, max(-127, (int)rintf(v[j].x * inv)));
        int q1 = min(127, max(-127, (int)rintf(v[j].y * inv)));
        int q2 = min(127, max(-127, (int)rintf(v[j].z * inv)));
        int q3 = min(127, max(-127, (int)rintf(v[j].w * inv)));
        qr[t + j * 256] = (q0 & 0xff) | ((q1 & 0xff) << 8) | ((q2 & 0xff) << 16) | ((q3 & 0xff) << 24);
    }
    if (t == 0) xscale[row] = scale;
}

// ---------------- kernel 4: int8 MFMA GEMM, B-from-global flatmm style ----------------
// BM=256, BN=128, BK=64. 4 waves, each 64(M) x 128(N) = 2x4 of 32x32x32.
// A: double-buffered LDS (2x16KB) via global_load_lds, staged 1 iter ahead.
// B: pre-shuffled Bp, per-fragment coalesced global->reg loads (L1 multicast).
__global__ void __launch_bounds__(256, 2) gemm_i8_kernel(const signed char* __restrict__ Aq,
                                                         const signed char* __restrict__ Bp,
                                                         const float* __restrict__ xscale,
                                                         const double* __restrict__ wsum,
                                                         float* __restrict__ C,
                                                         int M, int N, int K) {
    constexpr int BM = 256, BN = 128, BK = 64;
    __shared__ signed char As[2][BM * BK];     // 2 x 16KB

    const int tid = threadIdx.x;
    const int wave = tid >> 6;
    const int lane = tid & 63;
    const int l32 = lane & 31;
    const int half = lane >> 5;

    // XCD-aware block swizzle: same-bn column -> same XCD for B L2 locality
    int id = blockIdx.y * gridDim.x + blockIdx.x;
    int xcd = id & 7;
    int local = id >> 3;
    int bxl = local >> 5;          // 0..3
    int byl = local & 31;          // 0..31
    const int bm = byl * BM;
    const int bn = (bxl * 8 + xcd) * BN;

    v16i acc[2][4];
#pragma unroll
    for (int mt = 0; mt < 2; mt++)
#pragma unroll
        for (int nt = 0; nt < 4; nt++)
#pragma unroll
            for (int r = 0; r < 16; r++) acc[mt][nt][r] = 0;

    // A staging: 1024 segs of 16B per buffer; thread owns segs tid+j*256.
    // Seg s holds (row=s>>2, chunk=(s&3)^((row>>1)&3)) -> bank-conflict-free reads.
    const signed char* asrc[4];
    int soff[4];
#pragma unroll
    for (int j = 0; j < 4; j++) {
        int s = tid + j * 256;
        int r = s >> 2;
        int c = (s & 3) ^ ((r >> 1) & 3);
        asrc[j] = Aq + (size_t)(bm + r) * K + c * 16;
        soff[j] = s * 16;
    }

    // B: lane-contiguous fragment base
    const signed char* bbase = Bp + ((size_t)(bn >> 5) * (K >> 5)) * 1024 + lane * 16;
    const int kx = (l32 >> 1) & 3;   // read-side XOR

    // prologue: stage buffer 0
#pragma unroll
    for (int j = 0; j < 4; j++) GLOAD_LDS16(asrc[j], &As[0][soff[j]]);

    const int KT = K / BK;   // 64
    for (int kt = 0; kt < KT; ++kt) {
        __syncthreads();     // staging of As[kt&1] (issued last iter) completes here
        const int cur = kt & 1;
        if (kt + 1 < KT) {
            const int goff = (kt + 1) * BK;
#pragma unroll
            for (int j = 0; j < 4; j++) GLOAD_LDS16(asrc[j] + goff, &As[cur ^ 1][soff[j]]);
        }
        // B fragments: 8 coalesced 1KB wave-loads, compiler-scheduled vmcnt
        v4i bf[2][4];
        const int ksg = kt * 2;
#pragma unroll
        for (int nt = 0; nt < 4; nt++)
#pragma unroll
            for (int ks = 0; ks < 2; ks++)
                bf[ks][nt] = *(const v4i*)(bbase + (size_t)(nt * (K >> 5) + ksg + ks) * 1024);
        // A fragments from LDS (conflict-free swizzle)
        const v4i* As4 = (const v4i*)As[cur];
        v4i af[2][2];
#pragma unroll
        for (int mt = 0; mt < 2; mt++) {
            int row = wave * 64 + mt * 32 + l32;
#pragma unroll
            for (int ks = 0; ks < 2; ks++)
                af[ks][mt] = As4[row * 4 + ((ks * 2 + half) ^ kx)];
        }
#pragma unroll
        for (int ks = 0; ks < 2; ks++)
#pragma unroll
            for (int mt = 0; mt < 2; mt++)
#pragma unroll
                for (int nt = 0; nt < 4; nt++)
                    acc[mt][nt] = __builtin_amdgcn_mfma_i32_32x32x32_i8(af[ks][mt], bf[ks][nt],
                                                                        acc[mt][nt], 0, 0, 0);
    }

    // epilogue: 32x32 C/D layout: col = l32, row = 4*half + (r&3) + 8*(r>>2)
    float wsf = (float)(wsum[0] / (double)((size_t)N * K)) + EPS_F;
    const float wk = wsf / 127.0f;
#pragma unroll
    for (int mt = 0; mt < 2; mt++) {
        int rowbase = bm + wave * 64 + mt * 32 + 4 * half;
#pragma unroll
        for (int r = 0; r < 16; r++) {
            int gm = rowbase + (r & 3) + 8 * (r >> 2);
            float sc = xscale[gm] * wk;
            float* crow = C + (size_t)gm * N + bn + l32;
#pragma unroll
            for (int nt = 0; nt < 4; nt++)
                crow[nt * 32] = (float)acc[mt][nt][r] * sc;
        }
    }
}

extern "C" void kernel_launch(void* const* d_in, const int* in_sizes, int n_in,
                              void* d_out, int out_size, void* d_ws, size_t ws_size,
                              hipStream_t stream) {
    const float* x = (const float*)d_in[0];
    const float* w = (const float*)d_in[1];
    float* y = (float*)d_out;

    const int K = 4096, N = 4096;
    const int M = in_sizes[0] / K;       // 8192
    const int wcount = in_sizes[1];      // N*K

    double* wsum = (double*)d_ws;
    float* xscale = (float*)((char*)d_ws + 256);
    signed char* xq = (signed char*)((char*)d_ws + 256 + 65536);
    signed char* bp = xq + (size_t)M * K;

    hipMemsetAsync(wsum, 0, sizeof(double), stream);
    wabs_sum_kernel<<<1024, 256, 0, stream>>>(w, wsum, wcount / 4);
    wpack_kernel<<<(N * (K / 16)) / 256, 256, 0, stream>>>(w, wsum, bp, N, K);
    xquant_kernel<<<M, 256, 0, stream>>>(x, xq, xscale, K);
    dim3 grid(N / 128, M / 256);
    gemm_i8_kernel<<<grid, 256, 0, stream>>>(xq, bp, xscale, wsum, y, M, N, K);
}